// Round 8
// baseline (197.671 us; speedup 1.0000x reference)
//
#include <hip/hip_runtime.h>
#include <cstdint>
#include <cstddef>

typedef unsigned short u16;
typedef __attribute__((ext_vector_type(8))) short short8;
typedef __attribute__((ext_vector_type(8))) u16 ushort8;
typedef __attribute__((ext_vector_type(4))) float float4_t;

#define BB 8
#define NN 8192
#define DD 64
#define NITER 128            // 8192 cols / 64 cols-per-block-stage
#define TILE_SHORTS 8192     // 128 points * 64 k (bf16)
#define LDS_STRIDE 68        // 64 floats + 4 pad (bank spread)

__device__ inline u16 f32_to_bf16(float f) {
  unsigned u = __float_as_uint(f);
  u += 0x7FFFu + ((u >> 16) & 1u);   // RNE
  return (u16)(u >> 16);
}

// ---------------------------------------------------------------------------
// K1: one block = one 128x64 tile. Coalesced read-once -> LDS -> swizzled
// bf16 tile (MFMA fragment chunk order) + 0.5*|row|^2. Zeroes out[].
// Chunk layout per tile: [I(8)][s(2)] chunks of 1KB; within a chunk lane
// l (l=qq*16+rl) holds point I*16+rl, k = s*32+qq*8+j (j=0..7, 16B).
// [structure verified correct R6/R7]
// ---------------------------------------------------------------------------
__global__ __launch_bounds__(256) void pre_kernel(
    const float* __restrict__ x, const float* __restrict__ y,
    u16* __restrict__ xs, u16* __restrict__ ys,
    float* __restrict__ x2h, float* __restrict__ y2h,
    float* __restrict__ out)
{
  __shared__ float stage[128 * LDS_STRIDE];   // 34 KB

  const int bid = blockIdx.x;          // 1024: 0..511 -> x, 512..1023 -> y
  const int tid = threadIdx.x;

  if (bid == 0 && tid == 0) out[0] = 0.f;

  const bool isY = bid >= 512;
  const int t = bid & 511;             // tile id = b*64 + nt
  const float* src = (isY ? y : x) + (size_t)t * (128 * DD);
  u16* dst = (isY ? ys : xs) + (size_t)t * TILE_SHORTS;
  float* s2 = (isY ? y2h : x2h) + t * 128;

#pragma unroll
  for (int c = 0; c < 8; ++c) {
    const int idx = c * 256 + tid;     // float4 index within tile (0..2047)
    float4 f = ((const float4*)src)[idx];
    const int r = idx >> 4, kc = idx & 15;
    *(float4*)&stage[r * LDS_STRIDE + kc * 4] = f;
  }
  __syncthreads();

  {
    const int r = tid >> 1, half = tid & 1;
    const float* rp = &stage[r * LDS_STRIDE + half * 32];
    float ss = 0.f;
#pragma unroll
    for (int k = 0; k < 8; ++k) {
      float4 f = *(const float4*)&rp[k * 4];
      ss += f.x*f.x + f.y*f.y + f.z*f.z + f.w*f.w;
    }
    ss += __shfl_xor(ss, 1);
    if (half == 0) s2[r] = 0.5f * ss;
  }

  {
    const int w = tid >> 6, lane = tid & 63;
    const int qq = lane >> 4, rl = lane & 15;
#pragma unroll
    for (int u = 0; u < 4; ++u) {
      const int chunk = w * 4 + u;
      const int I = chunk >> 1, s = chunk & 1;
      const float* rp = &stage[(I*16 + rl) * LDS_STRIDE + s*32 + qq*8];
      ushort8 o;
#pragma unroll
      for (int j = 0; j < 8; ++j) o[j] = f32_to_bf16(rp[j]);
      *(ushort8*)(dst + chunk*512 + lane*8) = o;
    }
  }
}

// ---------------------------------------------------------------------------
// K2: main. Block = 64 rows (4 waves x 16 disjoint cols/stage); each block
// sweeps all 8192 cols in 128 stages. Software-pipelined, barrier-free:
// per stage [BLOAD(k+1)] [8 MFMA stage k] [EPI(k-1)] with acc banks A/B
// alternating by parity — the epilogue (pure max, C-init carries exact
// -(x^2+y^2)/2 so acc = -d^2/2) overlaps the next stage's MFMA drain.
// Live regs ~145: launch_bounds(256,3) caps ~168 — no spill (R4/R6 lesson:
// the 128x32 tile + 2 acc banks exceeds 256 and dies; 64x16 fits).
// Col-max partials -> bf16 colpart[b][rt][m] (error ~1e-2 on d, thr 0.32);
// row-max stays in registers -> a_min direct. Grid 1024 = 8 b x 128 rt.
// ---------------------------------------------------------------------------
__global__ __launch_bounds__(256, 3) void main_kernel(
    const u16* __restrict__ xs, const u16* __restrict__ ys,
    const float* __restrict__ x2h, const float* __restrict__ y2h,
    float* __restrict__ a_min, u16* __restrict__ colpart)
{
  __shared__ float rowbuf[4][64];

  const int bid = blockIdx.x;          // 1024
  const int b = bid & 7;               // XCD-affine
  const int rt = bid >> 3;             // 64-row tile, 0..127
  const int tid = threadIdx.x;
  const int w = tid >> 6, lane = tid & 63;
  const int l15 = lane & 15, q = lane >> 4;

  // ---- A fragments: 64 rows, both K-halves, pinned (32 VGPR) ----
  const u16* xs_tile = xs + (size_t)((b << 6) | (rt >> 1)) * TILE_SHORTS;
  short8 afr[4][2];
#pragma unroll
  for (int i = 0; i < 4; ++i)
#pragma unroll
    for (int s = 0; s < 2; ++s)
      afr[i][s] = *(const short8*)(xs_tile + ((((rt & 1)*4 + i)*2) + s)*512 + lane*8);

  // ---- -x2/2 per row (fp32 exact) ----
  float4_t negx2[4];
  const float* x2b = x2h + b*NN + rt*64;
#pragma unroll
  for (int i = 0; i < 4; ++i) {
    float4_t v = *(const float4_t*)(x2b + i*16 + q*4);
    negx2[i] = {-v[0], -v[1], -v[2], -v[3]};
  }

  float rowmax[4][4];
#pragma unroll
  for (int i = 0; i < 4; ++i)
#pragma unroll
    for (int r = 0; r < 4; ++r) rowmax[i][r] = -3.0e38f;

  const float* y2b = y2h + b*NN;
  const u16* ys_b  = ys + (size_t)(b << 6) * TILE_SHORTS;
  u16* colp        = colpart + (size_t)(b*NITER + rt) * NN;

  // stage T covers cols T*64 + w*16 + l15 (16-col group G = T*4 + w)
#define BLOAD(T, B0, B1, Y2)                                                   \
  do {                                                                         \
    const int G_ = (T)*4 + w;                                                  \
    const u16* gp_ = ys_b + (size_t)(G_ >> 3)*TILE_SHORTS + ((G_ & 7)*2)*512 + lane*8; \
    B0 = *(const short8*)gp_;                                                  \
    B1 = *(const short8*)(gp_ + 512);                                          \
    Y2 = y2b[(T)*64 + w*16 + l15];                                             \
  } while (0)

#define STAGE(ACC, B0, B1, Y2)                                                 \
  do {                                                                         \
    const float y2s_ = (Y2);                                                   \
    _Pragma("unroll") for (int i = 0; i < 4; ++i) {                            \
      float4_t ci = {negx2[i][0] - y2s_, negx2[i][1] - y2s_,                   \
                     negx2[i][2] - y2s_, negx2[i][3] - y2s_};                  \
      ACC[i] = __builtin_amdgcn_mfma_f32_16x16x32_bf16(afr[i][0], B0, ci, 0, 0, 0); \
    }                                                                          \
    _Pragma("unroll") for (int i = 0; i < 4; ++i)                              \
      ACC[i] = __builtin_amdgcn_mfma_f32_16x16x32_bf16(afr[i][1], B1, ACC[i], 0, 0, 0); \
  } while (0)

#define EPI(ACC, T)                                                            \
  do {                                                                         \
    float cm = fmaxf(fmaxf(ACC[0][0], ACC[0][1]), fmaxf(ACC[0][2], ACC[0][3]));\
    _Pragma("unroll") for (int i = 1; i < 4; ++i)                              \
      cm = fmaxf(cm, fmaxf(fmaxf(ACC[i][0], ACC[i][1]),                        \
                           fmaxf(ACC[i][2], ACC[i][3])));                      \
    cm = fmaxf(cm, __shfl_xor(cm, 16));                                        \
    cm = fmaxf(cm, __shfl_xor(cm, 32));                                        \
    if (q == 0) colp[(T)*64 + w*16 + l15] = f32_to_bf16(cm);                   \
    _Pragma("unroll") for (int i = 0; i < 4; ++i)                              \
      _Pragma("unroll") for (int r = 0; r < 4; ++r)                            \
        rowmax[i][r] = fmaxf(rowmax[i][r], ACC[i][r]);                         \
  } while (0)

  short8 bX0, bX1, bY0, bY1;
  float y2X, y2Y;
  float4_t accA[4], accB[4];

  // prologue
  BLOAD(0, bX0, bX1, y2X);
  BLOAD(1, bY0, bY1, y2Y);
  STAGE(accA, bX0, bX1, y2X);          // stage 0
  BLOAD(2, bX0, bX1, y2X);
  STAGE(accB, bY0, bY1, y2Y);          // stage 1
  EPI(accA, 0);

  for (int t = 2; t < NITER - 2; t += 2) {
    BLOAD(t + 1, bY0, bY1, y2Y);
    STAGE(accA, bX0, bX1, y2X);        // stage t (even)
    EPI(accB, t - 1);
    BLOAD(t + 2, bX0, bX1, y2X);
    STAGE(accB, bY0, bY1, y2Y);        // stage t+1 (odd)
    EPI(accA, t);
  }
  // tail: stages 126, 127
  BLOAD(NITER - 1, bY0, bY1, y2Y);
  STAGE(accA, bX0, bX1, y2X);          // stage 126
  EPI(accB, NITER - 3);
  STAGE(accB, bY0, bY1, y2Y);          // stage 127
  EPI(accA, NITER - 2);
  EPI(accB, NITER - 1);

#undef BLOAD
#undef STAGE
#undef EPI

  // ---- row side: shfl over l15 (cols), 4-wave LDS combine, a_min ----
#pragma unroll
  for (int i = 0; i < 4; ++i)
#pragma unroll
    for (int r = 0; r < 4; ++r) {
      float v = rowmax[i][r];
      v = fmaxf(v, __shfl_xor(v, 1));
      v = fmaxf(v, __shfl_xor(v, 2));
      v = fmaxf(v, __shfl_xor(v, 4));
      v = fmaxf(v, __shfl_xor(v, 8));
      rowmax[i][r] = v;
    }
  if (l15 == 0) {
#pragma unroll
    for (int i = 0; i < 4; ++i)
#pragma unroll
      for (int r = 0; r < 4; ++r)
        rowbuf[w][i*16 + q*4 + r] = rowmax[i][r];
  }
  __syncthreads();
  if (tid < 64) {
    float v = fmaxf(fmaxf(rowbuf[0][tid], rowbuf[1][tid]),
                    fmaxf(rowbuf[2][tid], rowbuf[3][tid]));   // -min(d^2)/2
    a_min[b*NN + rt*64 + tid] = sqrtf(fmaxf(-2.f * v, 0.f));
  }
}

// ---------------------------------------------------------------------------
// K3: col combine over 128 rt (bf16 partials) + sqrt, add a_min; block sum;
// atomicAdd scaled result into out.
// ---------------------------------------------------------------------------
__global__ __launch_bounds__(256) void reduce_kernel(
    const u16* __restrict__ colpart, const float* __restrict__ a_min,
    float* __restrict__ out)
{
  const int bid = blockIdx.x;          // 256
  const int tid = threadIdx.x;
  const int g = bid*256 + tid;         // 0..65535 = b*NN + m
  const int b = g >> 13, m = g & (NN - 1);

  const u16* cp = colpart + (size_t)b * NITER * NN + m;
  float vc = -3.0e38f;
#pragma unroll 8
  for (int rt = 0; rt < NITER; ++rt) {
    unsigned u = cp[(size_t)rt * NN];
    vc = fmaxf(vc, __uint_as_float(u << 16));
  }
  float s = sqrtf(fmaxf(-2.f * vc, 0.f))   // nearest-x for this y
          + a_min[g];                      // nearest-y for this x

#pragma unroll
  for (int d = 1; d < 64; d <<= 1) s += __shfl_xor(s, d);
  __shared__ float wsum[4];
  if ((tid & 63) == 0) wsum[tid >> 6] = s;
  __syncthreads();
  if (tid == 0)
    atomicAdd(out, (wsum[0] + wsum[1] + wsum[2] + wsum[3]) * (1.0f / 65536.0f));
}

// ---------------------------------------------------------------------------
extern "C" void kernel_launch(void* const* d_in, const int* in_sizes, int n_in,
                              void* d_out, int out_size, void* d_ws, size_t ws_size,
                              hipStream_t stream) {
  const float* x = (const float*)d_in[0];
  const float* y = (const float*)d_in[1];
  float* out = (float*)d_out;

  char* p = (char*)d_ws;
  u16* xs = (u16*)p;            p += (size_t)512 * 16384;   // 8 MiB
  u16* ys = (u16*)p;            p += (size_t)512 * 16384;   // 8 MiB
  float* x2h = (float*)p;       p += (size_t)65536 * 4;
  float* y2h = (float*)p;       p += (size_t)65536 * 4;
  float* a_min = (float*)p;     p += (size_t)65536 * 4;
  u16* colpart = (u16*)p;       // 8 b * 128 rt * 8192 m * 2 B = 16 MiB
  // total ~32.8 MiB (< the ~50 MiB the R3-R7 partial path already used)

  pre_kernel<<<dim3(1024), dim3(256), 0, stream>>>(x, y, xs, ys, x2h, y2h, out);
  main_kernel<<<dim3(1024), dim3(256), 0, stream>>>(xs, ys, x2h, y2h,
                                                    a_min, colpart);
  reduce_kernel<<<dim3(256), dim3(256), 0, stream>>>(colpart, a_min, out);
}

// Round 9
// 162.482 us; speedup vs baseline: 1.2166x; 1.2166x over previous
//
#include <hip/hip_runtime.h>
#include <cstdint>
#include <cstddef>

typedef unsigned short u16;
typedef __attribute__((ext_vector_type(8))) short short8;
typedef __attribute__((ext_vector_type(8))) u16 ushort8;
typedef __attribute__((ext_vector_type(4))) float float4_t;

#define BB 8
#define NN 8192
#define DD 64
#define NTILES 64            // 8192 / 128 column tiles
#define TILE_SHORTS 8192     // 128 points * 64 k (bf16)
#define LDS_STRIDE 68        // 64 floats + 4 pad (bank spread)

__device__ inline u16 f32_to_bf16(float f) {
  unsigned u = __float_as_uint(f);
  u += 0x7FFFu + ((u >> 16) & 1u);   // RNE
  return (u16)(u >> 16);
}

__device__ inline unsigned enc_ord(float f) {
  unsigned u = __float_as_uint(f);
  return (u & 0x80000000u) ? ~u : (u | 0x80000000u);
}
__device__ inline float dec_ord(unsigned u) {
  return __uint_as_float((u & 0x80000000u) ? (u & 0x7fffffffu) : ~u);
}

// ---------------------------------------------------------------------------
// K1: one block = one 128x64 tile. Coalesced read-once -> LDS -> swizzled
// bf16 tile (MFMA fragment chunk order) + 0.5*|row|^2. Zeroes out[] and, in
// the fallback path, the ordered-uint max buffers.  [verified R6/R7]
// Chunk layout per tile: [I(8)][s(2)] chunks of 1KB; within a chunk lane
// l (l=qq*16+rl) holds point I*16+rl, k = s*32+qq*8+j (j=0..7, 16B).
// ---------------------------------------------------------------------------
__global__ __launch_bounds__(256) void pre_kernel(
    const float* __restrict__ x, const float* __restrict__ y,
    u16* __restrict__ xs, u16* __restrict__ ys,
    float* __restrict__ x2h, float* __restrict__ y2h,
    unsigned* __restrict__ rowmax_u, unsigned* __restrict__ colmax_u,
    float* __restrict__ out, const int use_part)
{
  __shared__ float stage[128 * LDS_STRIDE];   // 34 KB

  const int bid = blockIdx.x;          // 1024: 0..511 -> x, 512..1023 -> y
  const int tid = threadIdx.x;

  if (!use_part) {
    if (bid < 256)      colmax_u[(bid << 8) | tid] = 0u;
    else if (bid < 512) rowmax_u[((bid - 256) << 8) | tid] = 0u;
  }
  if (bid == 0 && tid == 0) out[0] = 0.f;

  const bool isY = bid >= 512;
  const int t = bid & 511;             // tile id = b*64 + nt
  const float* src = (isY ? y : x) + (size_t)t * (128 * DD);
  u16* dst = (isY ? ys : xs) + (size_t)t * TILE_SHORTS;
  float* s2 = (isY ? y2h : x2h) + t * 128;

#pragma unroll
  for (int c = 0; c < 8; ++c) {
    const int idx = c * 256 + tid;     // float4 index within tile (0..2047)
    float4 f = ((const float4*)src)[idx];
    const int r = idx >> 4, kc = idx & 15;
    *(float4*)&stage[r * LDS_STRIDE + kc * 4] = f;
  }
  __syncthreads();

  {
    const int r = tid >> 1, half = tid & 1;
    const float* rp = &stage[r * LDS_STRIDE + half * 32];
    float ss = 0.f;
#pragma unroll
    for (int k = 0; k < 8; ++k) {
      float4 f = *(const float4*)&rp[k * 4];
      ss += f.x*f.x + f.y*f.y + f.z*f.z + f.w*f.w;
    }
    ss += __shfl_xor(ss, 1);
    if (half == 0) s2[r] = 0.5f * ss;
  }

  {
    const int w = tid >> 6, lane = tid & 63;
    const int qq = lane >> 4, rl = lane & 15;
#pragma unroll
    for (int u = 0; u < 4; ++u) {
      const int chunk = w * 4 + u;
      const int I = chunk >> 1, s = chunk & 1;
      const float* rp = &stage[(I*16 + rl) * LDS_STRIDE + s*32 + qq*8];
      ushort8 o;
#pragma unroll
      for (int j = 0; j < 8; ++j) o[j] = f32_to_bf16(rp[j]);
      *(ushort8*)(dst + chunk*512 + lane*8) = o;
    }
  }
}

// ---------------------------------------------------------------------------
// K2: main — the R3 loop body VERBATIM (proven 88 us @ 128 VGPR, no spill),
// with a 2-way column split for occupancy: grid 1024 = 8 b x 64 nt x 2 h,
// each block sweeps 32 of the 64 col-tiles. launch_bounds stays (256,2)
// (capping at 4 forces spills — R4); at 128 VGPR the HW naturally fits
// 4 blocks/CU, doubling waves/SIMD to fill the MFMA issue gaps.
// Row-max exits via 2-way rowpart partials (R2-verified mechanism).
// DO NOT add acc double-buffering / unrolling here (R4/R6/R8 all lost).
// ---------------------------------------------------------------------------
__global__ __launch_bounds__(256, 2) void main_kernel(
    const u16* __restrict__ xs, const u16* __restrict__ ys,
    const float* __restrict__ x2h, const float* __restrict__ y2h,
    float* __restrict__ rowpart, float* __restrict__ colpart,
    unsigned* __restrict__ rowmax_u, unsigned* __restrict__ colmax_u,
    const int use_part)
{
  __shared__ float rowbuf[4][128];

  const int bid = blockIdx.x;            // 1024
  const int b   = bid & 7;               // XCD-affine
  const int nt  = (bid >> 3) & 63;
  const int h   = bid >> 9;              // 0..1 column half
  const int mt_start = h << 5, mt_end = mt_start + 32;
  const int tid = threadIdx.x;
  const int w = tid >> 6, lane = tid & 63;   // w = column-slice owner
  const int l15 = lane & 15, q = lane >> 4;
  const int n0 = nt << 7;

  // ---- A fragments: all 128 rows, both K-halves, pinned in registers ----
  const u16* xs_tile = xs + (size_t)((b << 6) | nt) * TILE_SHORTS;
  short8 afr[8][2];
#pragma unroll
  for (int i = 0; i < 8; ++i)
#pragma unroll
    for (int s = 0; s < 2; ++s)
      afr[i][s] = *(const short8*)(xs_tile + (i*2 + s)*512 + lane*8);

  // ---- C-init quads: -x2/2 per row (fp32 exact) ----
  float4_t negx2[8];
  const float* x2b = x2h + b*NN + n0;
#pragma unroll
  for (int i = 0; i < 8; ++i) {
    float4_t v = *(const float4_t*)(x2b + i*16 + q*4);
    negx2[i] = {-v[0], -v[1], -v[2], -v[3]};
  }

  float rowmax[8][4];
#pragma unroll
  for (int i = 0; i < 8; ++i)
#pragma unroll
    for (int r = 0; r < 4; ++r) rowmax[i][r] = -3.0e38f;

  const float* y2b = y2h + b*NN;
  const u16* ys_b  = ys + (size_t)(b << 6) * TILE_SHORTS;
  float* colp      = colpart + (size_t)((b << 6) | nt) * NN;
  unsigned* colu   = colmax_u + b*NN;

  // ---- register prefetch for mt_start ----
  short8 bcur[2][2];
  float y2cur[2];
#pragma unroll
  for (int j = 0; j < 2; ++j) {
#pragma unroll
    for (int s = 0; s < 2; ++s)
      bcur[j][s] = *(const short8*)(ys_b + (size_t)mt_start*TILE_SHORTS
                                    + ((2*w + j)*2 + s)*512 + lane*8);
    y2cur[j] = y2b[mt_start*128 + w*32 + j*16 + l15];
  }

  for (int mt = mt_start; mt < mt_end; ++mt) {
    // prefetch mt+1 (clamped; uniform predicate-free codegen)
    const int mtn = (mt + 1 < mt_end) ? (mt + 1) : mt_start;
    short8 bnext[2][2];
    float y2next[2];
    const u16* g = ys_b + (size_t)mtn * TILE_SHORTS;
#pragma unroll
    for (int j = 0; j < 2; ++j) {
#pragma unroll
      for (int s = 0; s < 2; ++s)
        bnext[j][s] = *(const short8*)(g + ((2*w + j)*2 + s)*512 + lane*8);
      y2next[j] = y2b[mtn*128 + w*32 + j*16 + l15];
    }

    float cmax[2];
#pragma unroll
    for (int j = 0; j < 2; ++j) {
      // acc = xy - x2/2 (C carries exact fp32 -x2/2); j-sequential keeps
      // live accumulators at 8 x float4
      float4_t acc[8];
#pragma unroll
      for (int i = 0; i < 8; ++i)
        acc[i] = __builtin_amdgcn_mfma_f32_16x16x32_bf16(afr[i][0], bcur[j][0], negx2[i], 0, 0, 0);
#pragma unroll
      for (int i = 0; i < 8; ++i)
        acc[i] = __builtin_amdgcn_mfma_f32_16x16x32_bf16(afr[i][1], bcur[j][1], acc[i], 0, 0, 0);

      // col side: pure max over rows in-lane
      float m01 = fmaxf(fmaxf(acc[0][0], acc[0][1]), fmaxf(acc[0][2], acc[0][3]));
#pragma unroll
      for (int i = 1; i < 8; ++i) {
        float mi = fmaxf(fmaxf(acc[i][0], acc[i][1]), fmaxf(acc[i][2], acc[i][3]));
        m01 = fmaxf(m01, mi);
      }
      cmax[j] = m01;

      // row side: rowmax = max(acc - y2/2) = -min(d^2)/2
      const float y2j = y2cur[j];
#pragma unroll
      for (int i = 0; i < 8; ++i)
#pragma unroll
        for (int r = 0; r < 4; ++r)
          rowmax[i][r] = fmaxf(rowmax[i][r], acc[i][r] - y2j);
    }

    // col-max: combine q-groups (rows) via shuffles; wave-private, no barrier
#pragma unroll
    for (int j = 0; j < 2; ++j) {
      cmax[j] = fmaxf(cmax[j], __shfl_xor(cmax[j], 16));
      cmax[j] = fmaxf(cmax[j], __shfl_xor(cmax[j], 32));
    }
    float cv = (q & 1) ? cmax[1] : cmax[0];
    const int m = (mt << 7) + w*32 + q*16 + l15;   // valid for q<2
    if (q < 2) {
      if (use_part) colp[m] = cv;
      else          atomicMax(&colu[m], enc_ord(cv));
    }

#pragma unroll
    for (int j = 0; j < 2; ++j) {
#pragma unroll
      for (int s = 0; s < 2; ++s) bcur[j][s] = bnext[j][s];
      y2cur[j] = y2next[j];
    }
  }

  // ---- row side finalize: shfl over cols (l15), then 4-wave LDS combine ----
#pragma unroll
  for (int i = 0; i < 8; ++i)
#pragma unroll
    for (int r = 0; r < 4; ++r) {
      float v = rowmax[i][r];
      v = fmaxf(v, __shfl_xor(v, 1));
      v = fmaxf(v, __shfl_xor(v, 2));
      v = fmaxf(v, __shfl_xor(v, 4));
      v = fmaxf(v, __shfl_xor(v, 8));
      rowmax[i][r] = v;
    }
  if (l15 == 0) {
#pragma unroll
    for (int i = 0; i < 8; ++i)
#pragma unroll
      for (int r = 0; r < 4; ++r)
        rowbuf[w][i*16 + q*4 + r] = rowmax[i][r];
  }
  __syncthreads();
  if (tid < 128) {
    float v = fmaxf(fmaxf(rowbuf[0][tid], rowbuf[1][tid]),
                    fmaxf(rowbuf[2][tid], rowbuf[3][tid]));   // -min(d^2)/2
    if (use_part) rowpart[(size_t)((h << 9) | (b << 6) | nt) * 128 + tid] = v;
    else          atomicMax(&rowmax_u[b*NN + n0 + tid], enc_ord(v));
  }
}

// ---------------------------------------------------------------------------
// K3: col combine over 64 nt + sqrt; row combine over 2 h + sqrt; block sum;
// atomicAdd scaled result into out.
// ---------------------------------------------------------------------------
__global__ __launch_bounds__(256) void reduce_kernel(
    const float* __restrict__ rowpart, const float* __restrict__ colpart,
    const unsigned* __restrict__ rowmax_u, const unsigned* __restrict__ colmax_u,
    const float* __restrict__ y2h, float* __restrict__ out,
    const int use_part)
{
  const int bid = blockIdx.x;          // 256
  const int tid = threadIdx.x;
  const int g = bid*256 + tid;         // 0..65535
  const int b = g >> 13, m = g & (NN - 1);

  float vc, vr;
  if (use_part) {
    vc = -3.0e38f;
#pragma unroll 8
    for (int nt = 0; nt < 64; ++nt)
      vc = fmaxf(vc, colpart[(size_t)((b << 6) | nt) * NN + m]);
    const int nt = m >> 7, r = m & 127;
    float r0 = rowpart[(size_t)((0 << 9) | (b << 6) | nt) * 128 + r];
    float r1 = rowpart[(size_t)((1 << 9) | (b << 6) | nt) * 128 + r];
    vr = fmaxf(r0, r1);
  } else {
    vc = dec_ord(colmax_u[g]);
    vr = dec_ord(rowmax_u[g]);
  }
  float s = sqrtf(fmaxf(2.f*(y2h[g] - vc), 0.f))   // nearest-x for this y
          + sqrtf(fmaxf(-2.f*vr, 0.f));            // nearest-y for this x

#pragma unroll
  for (int d = 1; d < 64; d <<= 1) s += __shfl_xor(s, d);
  __shared__ float wsum[4];
  if ((tid & 63) == 0) wsum[tid >> 6] = s;
  __syncthreads();
  if (tid == 0)
    atomicAdd(out, (wsum[0] + wsum[1] + wsum[2] + wsum[3]) * (1.0f / 65536.0f));
}

// ---------------------------------------------------------------------------
extern "C" void kernel_launch(void* const* d_in, const int* in_sizes, int n_in,
                              void* d_out, int out_size, void* d_ws, size_t ws_size,
                              hipStream_t stream) {
  const float* x = (const float*)d_in[0];
  const float* y = (const float*)d_in[1];
  float* out = (float*)d_out;

  char* p = (char*)d_ws;
  u16* xs = (u16*)p;            p += (size_t)512 * 16384;   // 8 MiB
  u16* ys = (u16*)p;            p += (size_t)512 * 16384;   // 8 MiB
  float* x2h = (float*)p;       p += (size_t)65536 * 4;
  float* y2h = (float*)p;       p += (size_t)65536 * 4;
  char* tail = p;
  // partial path: colpart 16 MiB + rowpart 512 KiB
  float* colpart = (float*)tail;
  float* rowpart = (float*)(tail + (size_t)512 * 8192 * 4);
  // atomic fallback: two 256 KiB ordered-uint max buffers
  unsigned* colmax_u = (unsigned*)tail;
  unsigned* rowmax_u = (unsigned*)(tail + (size_t)65536 * 4);
  const size_t need_part = (size_t)(tail - (char*)d_ws) +
                           (size_t)512 * 8192 * 4 + (size_t)1024 * 128 * 4;
  const int use_part = (ws_size >= need_part) ? 1 : 0;

  pre_kernel<<<dim3(1024), dim3(256), 0, stream>>>(x, y, xs, ys, x2h, y2h,
                                                   rowmax_u, colmax_u, out,
                                                   use_part);
  main_kernel<<<dim3(1024), dim3(256), 0, stream>>>(xs, ys, x2h, y2h,
                                                    rowpart, colpart,
                                                    rowmax_u, colmax_u,
                                                    use_part);
  reduce_kernel<<<dim3(256), dim3(256), 0, stream>>>(rowpart, colpart,
                                                     rowmax_u, colmax_u, y2h,
                                                     out, use_part);
}